// Round 1
// 360.525 us; speedup vs baseline: 1.0060x; 1.0060x over previous
//
#include <hip/hip_runtime.h>
#include <hip/hip_bf16.h>
#include <hip/hip_fp16.h>

#define NEG_SLOPE 0.2f
#define NBUCK_MAX 256   // buckets of 512 nodes; 100k nodes -> 196 buckets
#define BCAP 12288      // fixed bucket capacity (mean 8163, sigma ~90 -> 45 sigma slack)

__device__ __forceinline__ float lrelu(float v) { return v >= 0.f ? v : NEG_SLOPE * v; }

__device__ __forceinline__ float wave_sum(float v) {
    for (int o = 32; o; o >>= 1) v += __shfl_down(v, o, 64);
    return v;
}

__device__ __forceinline__ void h8_to_f(const uint4 v, float* f) {
    float2 a = __half22float2(*(const __half2*)&v.x);
    float2 b = __half22float2(*(const __half2*)&v.y);
    float2 c = __half22float2(*(const __half2*)&v.z);
    float2 d = __half22float2(*(const __half2*)&v.w);
    f[0] = a.x; f[1] = a.y; f[2] = b.x; f[3] = b.y;
    f[4] = c.x; f[5] = c.y; f[6] = d.x; f[7] = d.y;
}

// ce1[h] = dot(We1[h*64..], ae1[h*64..]) — wave h computes head h. 256 threads.
__device__ __forceinline__ void compute_ce1(const float* __restrict__ We1,
                                            const float* __restrict__ ae1,
                                            float* ce /*shared[4]*/) {
    int t = threadIdx.x;
    float p = wave_sum(We1[t] * ae1[t]);
    if ((t & 63) == 0) ce[t >> 6] = p;
    __syncthreads();
}

__device__ __forceinline__ float compute_ce2(const float* __restrict__ We2,
                                             const float* __restrict__ ae2,
                                             float* sh /*shared[1]*/) {
    int t = threadIdx.x;
    if (t < 64) {
        float p = wave_sum(We2[t] * ae2[t]);
        if (t == 0) sh[0] = p;
    }
    __syncthreads();
    return sh[0];
}

// ---------------- Layer-1 prep: al_s1/al_d1; init bucket_cur; block 0 computes V -----
__global__ __launch_bounds__(256) void prep1_kernel(
    const float* __restrict__ x, const float* __restrict__ W1,
    const float* __restrict__ as1, const float* __restrict__ ad1,
    const float* __restrict__ W2, const float* __restrict__ b1,
    float* __restrict__ al_s1, float* __restrict__ al_d1,
    int* __restrict__ bucket_cur, float* __restrict__ V, int N) {
    __shared__ float cs0[4], cs1[4], cd0[4], cd1[4];
    int t = threadIdx.x;
    if (blockIdx.x == 0) bucket_cur[t] = t * BCAP;
    {
        float a = as1[t], d = ad1[t], u0 = W1[t], u1 = W1[256 + t];
        float p0 = wave_sum(u0 * a);
        float p1 = wave_sum(u1 * a);
        float q0 = wave_sum(u0 * d);
        float q1 = wave_sum(u1 * d);
        if ((t & 63) == 0) {
            int h = t >> 6;
            cs0[h] = p0; cs1[h] = p1; cd0[h] = q0; cd1[h] = q1;
        }
    }
    __syncthreads();
    int n = blockIdx.x * 256 + t;
    if (n < N) {
        float2 xs = ((const float2*)x)[n];
        float4 vs, vd;
        vs.x = xs.x * cs0[0] + xs.y * cs1[0];
        vs.y = xs.x * cs0[1] + xs.y * cs1[1];
        vs.z = xs.x * cs0[2] + xs.y * cs1[2];
        vs.w = xs.x * cs0[3] + xs.y * cs1[3];
        vd.x = xs.x * cd0[0] + xs.y * cd1[0];
        vd.y = xs.x * cd0[1] + xs.y * cd1[1];
        vd.z = xs.x * cd0[2] + xs.y * cd1[2];
        vd.w = xs.x * cd0[3] + xs.y * cd1[3];
        ((float4*)al_s1)[n] = vs;
        ((float4*)al_d1)[n] = vd;
    }
    // block 0 epilogue: V0[h,j] = W1[0,h,:]@W2^h[:,j], V1 likewise, c = b1@W2
    if (blockIdx.x == 0) {
        int h = t >> 6, j = t & 63;
        float v0 = 0.f, v1 = 0.f;
        for (int k = 0; k < 64; ++k) {
            float w2 = W2[(h * 64 + k) * 64 + j];
            v0 += W1[h * 64 + k] * w2;
            v1 += W1[256 + h * 64 + k] * w2;
        }
        V[t] = v0;
        V[256 + t] = v1;
        if (t < 64) {
            float c = 0.f;
            for (int i = 0; i < 256; ++i) c += b1[i] * W2[i * 64 + t];
            V[512 + t] = c;
        }
    }
}

// ---------------- Pass A: bin edges into fixed-capacity 512-node buckets -------------
// ebits = (src<<15) | ea15 ; bmeta = (dst_local<<21) | eid   (src<2^17, E<2^21)
__global__ __launch_bounds__(256) void binA_kernel(
    const int* __restrict__ ei, const float* __restrict__ ea,
    int* __restrict__ bucket_cur, unsigned* __restrict__ ebits,
    int* __restrict__ bmeta, int E, int nbuck) {
    __shared__ int lcount[NBUCK_MAX];
    __shared__ int lbase[NBUCK_MAX];
    __shared__ int lcur[NBUCK_MAX];
    int chunk = (E + gridDim.x - 1) / gridDim.x;
    int e0 = blockIdx.x * chunk;
    int e1 = min(e0 + chunk, E);
    for (int i = threadIdx.x; i < nbuck; i += 256) lcount[i] = 0;
    __syncthreads();
    for (int e = e0 + threadIdx.x; e < e1; e += 256)
        atomicAdd(&lcount[ei[E + e] >> 9], 1);
    __syncthreads();
    for (int i = threadIdx.x; i < nbuck; i += 256) {
        lbase[i] = lcount[i] ? atomicAdd(&bucket_cur[i], lcount[i]) : 0;
        lcur[i] = 0;
    }
    __syncthreads();
    for (int e = e0 + threadIdx.x; e < e1; e += 256) {
        int d = ei[E + e];
        int b = d >> 9;
        int pos = lbase[b] + atomicAdd(&lcur[b], 1);
        unsigned q = (unsigned)(ea[e] * 32767.f + 0.5f);
        q = min(q, 32767u);
        ebits[pos] = (((unsigned)ei[e]) << 15) | q;
        bmeta[pos] = ((d & 511) << 21) | e;
    }
}

// ---------------- Pass B: per bucket — LDS deg-histogram, local scan, exact scatter ----
// deg/offs written sequentially; csr_se/csr_eid live in the fixed bucket region.
__global__ __launch_bounds__(256) void binB_kernel(
    const unsigned* __restrict__ ebits, const int* __restrict__ bmeta,
    const int* __restrict__ bucket_cur,
    int* __restrict__ deg, int* __restrict__ offs,
    unsigned* __restrict__ csr_se, int* __restrict__ csr_eid, int N) {
    __shared__ int lcnt[512];
    __shared__ int lofs[512];
    __shared__ int lcur[512];
    int b = blockIdx.x;
    int n0 = b << 9;
    int t = threadIdx.x;
    lcnt[t] = 0; lcnt[t + 256] = 0;
    __syncthreads();
    int bstart = b * BCAP;
    int bend = bucket_cur[b];      // post-binA == region fill end
    for (int p = bstart + t; p < bend; p += 256)
        atomicAdd(&lcnt[((unsigned)bmeta[p]) >> 21], 1);
    __syncthreads();
    int a0 = lcnt[2 * t], a1 = lcnt[2 * t + 1];
    __shared__ int psum[256];
    psum[t] = a0 + a1;
    __syncthreads();
    for (int o = 1; o < 256; o <<= 1) {
        int a = (t >= o) ? psum[t - o] : 0;
        __syncthreads();
        psum[t] += a;
        __syncthreads();
    }
    int excl = psum[t] - (a0 + a1);
    lofs[2 * t] = excl;
    lofs[2 * t + 1] = excl + a0;
    lcur[2 * t] = bstart + excl;
    lcur[2 * t + 1] = bstart + excl + a0;
    __syncthreads();
    for (int i = t; i < 512; i += 256) {
        int n = n0 + i;
        if (n < N) {
            deg[n] = lcnt[i];
            offs[n] = bstart + lofs[i] + lcnt[i];   // segment END (fixed address space)
        }
    }
    for (int p = bstart + t; p < bend; p += 256) {
        int meta = bmeta[p];
        int pos = atomicAdd(&lcur[((unsigned)meta) >> 21], 1);
        csr_se[pos] = ebits[p];
        csr_eid[pos] = meta & 0x1FFFFF;
    }
}

// ---------------- Layer-1 aggregation, rank-2, no-max softmax (logits bounded) --------
// Unrolled x2: two edges' loads issued before either edge's exp/FMA work (MLP).
__global__ __launch_bounds__(256) void aggX_kernel(
    const unsigned* __restrict__ csr_se, const int* __restrict__ offs,
    const int* __restrict__ deg,
    const float* __restrict__ al_s1, const float* __restrict__ al_d1,
    const float* __restrict__ x,
    const float* __restrict__ We1, const float* __restrict__ ae1,
    float2* __restrict__ XA, int N) {
    __shared__ float ce[4];
    compute_ce1(We1, ae1, ce);
    int t = blockIdx.x * 256 + threadIdx.x;
    int n = t >> 2, h = t & 3;
    if (n >= N) return;
    int dc = deg[n];
    int start = offs[n] - dc;
    float ald = al_d1[4 * n + h];
    float ceh = ce[h] * (1.f / 32767.f);
    const float2* x2 = (const float2*)x;
    float z = 0.f, X0 = 0.f, X1 = 0.f;
    int j = 0;
    for (; j + 2 <= dc; j += 2) {
        unsigned w0 = csr_se[start + j];
        unsigned w1 = csr_se[start + j + 1];
        int s0 = w0 >> 15, s1 = w1 >> 15;
        float als0 = al_s1[4 * s0 + h];
        float als1 = al_s1[4 * s1 + h];
        float2 xs0 = x2[s0];
        float2 xs1 = x2[s1];
        float e0 = __expf(lrelu(als0 + ald + (float)(w0 & 32767u) * ceh));
        float e1 = __expf(lrelu(als1 + ald + (float)(w1 & 32767u) * ceh));
        z += e0 + e1;
        X0 += e0 * xs0.x + e1 * xs1.x;
        X1 += e0 * xs0.y + e1 * xs1.y;
    }
    if (j < dc) {
        unsigned w = csr_se[start + j];
        int s = w >> 15;
        float als = al_s1[4 * s + h];
        float2 xs = x2[s];
        float ex = __expf(lrelu(als + ald + (float)(w & 32767u) * ceh));
        z += ex;
        X0 += ex * xs.x;
        X1 += ex * xs.y;
    }
    float inv = 1.f / (z + 1e-16f);
    XA[(size_t)4 * n + h] = make_float2(X0 * inv, X1 * inv);
}

// ---------------- h2 from X: 8x64 matvec per node + alpha dots; h2 stored fp16 -------
__global__ __launch_bounds__(256) void hx_kernel(
    const float2* __restrict__ XA, const float* __restrict__ V,
    const float* __restrict__ as2, const float* __restrict__ ad2,
    __half* __restrict__ h2h, float* __restrict__ al_s2, float* __restrict__ al_d2,
    int N) {
    __shared__ float sV0[256], sV1[256], sC[64];
    for (int i = threadIdx.x; i < 256; i += 256) { sV0[i] = V[i]; sV1[i] = V[256 + i]; }
    if (threadIdx.x < 64) sC[threadIdx.x] = V[512 + threadIdx.x];
    __syncthreads();
    int wave = threadIdx.x >> 6, lane = threadIdx.x & 63;
    int n0 = (blockIdx.x * 4 + wave) * 4;
    float a_s = as2[lane], a_d = ad2[lane];
    for (int r = 0; r < 4; ++r) {
        int n = n0 + r;
        if (n >= N) break;
        float acc = sC[lane];
#pragma unroll
        for (int h = 0; h < 4; ++h) {
            float2 xv = XA[4 * n + h];
            acc += xv.x * sV0[h * 64 + lane] + xv.y * sV1[h * 64 + lane];
        }
        h2h[(size_t)n * 64 + lane] = __float2half(acc);
        float sv = wave_sum(acc * a_s);
        float dv = wave_sum(acc * a_d);
        if (lane == 0) { al_s2[n] = sv; al_d2[n] = dv; }
    }
}

// ---------------- Layer-2 fused softmax+message: ex and z computed inline ------------
// Eighth-wave (8 lanes x 8 halves) per edge; wave per node; no-max softmax (bounded
// logits, validated R12). Unrolled x2: 16 edges in flight per wave iteration; both
// h2 row gathers issued before the exp work. Invalid lanes hit row 0 (hot line), ex=0.
__global__ __launch_bounds__(256) void msg2_kernel(
    const unsigned* __restrict__ csr_se, const int* __restrict__ offs,
    const int* __restrict__ deg,
    const float* __restrict__ al_s2, const float* __restrict__ al_d2,
    const float* __restrict__ We2, const float* __restrict__ ae2,
    const __half* __restrict__ h2h, float* __restrict__ out2, int N) {
    __shared__ float sh[1];
    float ce2 = compute_ce2(We2, ae2, sh) * (1.f / 32767.f);
    int wave = threadIdx.x >> 6, lane = threadIdx.x & 63;
    int sub = lane >> 3, sl = lane & 7;
    int n = blockIdx.x * 4 + wave;
    if (n >= N) return;
    int dc = deg[n];
    int start = offs[n] - dc;
    float ald = al_d2[n];
    const uint4* h8 = (const uint4*)h2h;   // row = 8 uint4
    float acc[8] = {0.f, 0.f, 0.f, 0.f, 0.f, 0.f, 0.f, 0.f};
    float z = 0.f;
    for (int j0 = 0; j0 < dc; j0 += 16) {
        int jA = j0 + sub;
        int jB = jA + 8;
        bool vA = jA < dc, vB = jB < dc;
        unsigned wA = vA ? csr_se[start + jA] : 0u;
        unsigned wB = vB ? csr_se[start + jB] : 0u;
        int sA = wA >> 15;
        int sB = wB >> 15;
        uint4 hvA = h8[(size_t)sA * 8 + sl];
        uint4 hvB = h8[(size_t)sB * 8 + sl];
        float exA = 0.f, exB = 0.f;
        if (vA) exA = __expf(lrelu(al_s2[sA] + ald + (float)(wA & 32767u) * ce2));
        if (vB) exB = __expf(lrelu(al_s2[sB] + ald + (float)(wB & 32767u) * ce2));
        float hfA[8], hfB[8];
        h8_to_f(hvA, hfA);
        h8_to_f(hvB, hfB);
#pragma unroll
        for (int k = 0; k < 8; ++k) acc[k] += exA * hfA[k] + exB * hfB[k];
        z += exA + exB;
    }
    // reduce across the 8 sub-groups (lanes sub*8+sl); z reduces identically
#pragma unroll
    for (int k = 0; k < 8; ++k) {
        acc[k] += __shfl_down(acc[k], 32, 64);
        acc[k] += __shfl_down(acc[k], 16, 64);
        acc[k] += __shfl_down(acc[k], 8, 64);
    }
    z += __shfl_down(z, 32, 64);
    z += __shfl_down(z, 16, 64);
    z += __shfl_down(z, 8, 64);
    if (sub == 0) {
        float inv = 1.f / (z + 1e-16f);
        float4* o4 = (float4*)out2;
        o4[(size_t)n * 16 + sl * 2] =
            make_float4(acc[0] * inv, acc[1] * inv, acc[2] * inv, acc[3] * inv);
        o4[(size_t)n * 16 + sl * 2 + 1] =
            make_float4(acc[4] * inv, acc[5] * inv, acc[6] * inv, acc[7] * inv);
    }
}

// ---------------- g = Wr1^T (out2 + b2), stored fp16 ----------------
__global__ __launch_bounds__(256) void g_kernel(
    const float* __restrict__ out2, const float* __restrict__ b2,
    const float* __restrict__ Wr1, __half* __restrict__ g_h, int N) {
    __shared__ float W[64 * 64];
    __shared__ float rows[4][4][64];
    for (int i = threadIdx.x; i < 64 * 64; i += 256) W[i] = Wr1[i];
    __syncthreads();
    int wave = threadIdx.x >> 6, lane = threadIdx.x & 63;
    int n0 = (blockIdx.x * 4 + wave) * 4;
    for (int r = 0; r < 4; ++r) {
        int n = n0 + r;
        rows[wave][r][lane] = (n < N) ? (out2[(size_t)n * 64 + lane] + b2[lane]) : 0.f;
    }
    float a0 = 0.f, a1 = 0.f, a2 = 0.f, a3 = 0.f;
#pragma unroll 8
    for (int k = 0; k < 64; ++k) {
        float w = W[k * 64 + lane];
        a0 += rows[wave][0][k] * w;
        a1 += rows[wave][1][k] * w;
        a2 += rows[wave][2][k] * w;
        a3 += rows[wave][3][k] * w;
    }
    float as[4] = {a0, a1, a2, a3};
    for (int r = 0; r < 4; ++r) {
        int n = n0 + r;
        if (n < N) g_h[(size_t)n * 64 + lane] = __float2half(as[r]);
    }
}

// ---------------- Edge regressor, CSR order, fp16 g: invalid lanes hit row 0 ---------
// Unrolled x2: both g row gathers issued before the ReLU-dot work.
__global__ __launch_bounds__(256) void edge_csr_kernel(
    const unsigned* __restrict__ csr_se, const int* __restrict__ csr_eid,
    const int* __restrict__ offs, const int* __restrict__ deg,
    const __half* __restrict__ g_h,
    const float* __restrict__ br1, const float* __restrict__ Wr2,
    const float* __restrict__ br2, float* __restrict__ out, int N) {
    int wave = threadIdx.x >> 6, lane = threadIdx.x & 63;
    int sub = lane >> 3, sl = lane & 7;
    int n = blockIdx.x * 4 + wave;
    if (n >= N) return;
    const uint4* g8 = (const uint4*)g_h;
    float gd[8], w2[8];
    {
        uint4 gv = g8[(size_t)n * 8 + sl];
        h8_to_f(gv, gd);
        float4 brA = ((const float4*)br1)[sl * 2], brB = ((const float4*)br1)[sl * 2 + 1];
        gd[0] += brA.x; gd[1] += brA.y; gd[2] += brA.z; gd[3] += brA.w;
        gd[4] += brB.x; gd[5] += brB.y; gd[6] += brB.z; gd[7] += brB.w;
        float4 wA = ((const float4*)Wr2)[sl * 2], wB = ((const float4*)Wr2)[sl * 2 + 1];
        w2[0] = wA.x; w2[1] = wA.y; w2[2] = wA.z; w2[3] = wA.w;
        w2[4] = wB.x; w2[5] = wB.y; w2[6] = wB.z; w2[7] = wB.w;
    }
    float br2v = br2[0];
    int dc = deg[n];
    int start = offs[n] - dc;
    for (int j0 = 0; j0 < dc; j0 += 16) {
        int jA = j0 + sub;
        int jB = jA + 8;
        bool vA = jA < dc, vB = jB < dc;
        int idxA = start + (vA ? jA : 0);
        int idxB = start + (vB ? jB : 0);
        int srcA = vA ? (int)(csr_se[idxA] >> 15) : 0;
        int srcB = vB ? (int)(csr_se[idxB] >> 15) : 0;
        uint4 gvA = g8[(size_t)srcA * 8 + sl];
        uint4 gvB = g8[(size_t)srcB * 8 + sl];
        float gsA[8], gsB[8];
        h8_to_f(gvA, gsA);
        h8_to_f(gvB, gsB);
        float vAa = 0.f, vBa = 0.f;
#pragma unroll
        for (int k = 0; k < 8; ++k) {
            vAa += fmaxf(gd[k] + gsA[k], 0.f) * w2[k];
            vBa += fmaxf(gd[k] + gsB[k], 0.f) * w2[k];
        }
        vAa += __shfl_down(vAa, 4, 64);
        vAa += __shfl_down(vAa, 2, 64);
        vAa += __shfl_down(vAa, 1, 64);
        vBa += __shfl_down(vBa, 4, 64);
        vBa += __shfl_down(vBa, 2, 64);
        vBa += __shfl_down(vBa, 1, 64);
        if (sl == 0) {
            if (vA) out[csr_eid[idxA]] = vAa + br2v;
            if (vB) out[csr_eid[idxB]] = vBa + br2v;
        }
    }
}

extern "C" void kernel_launch(void* const* d_in, const int* in_sizes, int n_in,
                              void* d_out, int out_size, void* d_ws, size_t ws_size,
                              hipStream_t stream) {
    const float* x    = (const float*)d_in[0];
    const int*   ei   = (const int*)d_in[1];
    const float* ea   = (const float*)d_in[2];
    const float* W1   = (const float*)d_in[3];
    const float* We1  = (const float*)d_in[4];
    const float* as1  = (const float*)d_in[5];
    const float* ad1  = (const float*)d_in[6];
    const float* ae1  = (const float*)d_in[7];
    const float* b1   = (const float*)d_in[8];
    const float* W2   = (const float*)d_in[9];
    const float* We2  = (const float*)d_in[10];
    const float* as2  = (const float*)d_in[11];
    const float* ad2  = (const float*)d_in[12];
    const float* ae2  = (const float*)d_in[13];
    const float* b2   = (const float*)d_in[14];
    const float* Wr1  = (const float*)d_in[15];
    const float* br1  = (const float*)d_in[16];
    const float* Wr2  = (const float*)d_in[17];
    const float* br2  = (const float*)d_in[18];
    float* out = (float*)d_out;

    const int N = in_sizes[0] / 2;
    const int E = in_sizes[2];
    const int nbuck = (N + 511) >> 9;
    const size_t capE = (size_t)nbuck * BCAP;   // fixed-capacity CSR address space

    // workspace layout (~85 MB)
    float* ws = (float*)d_ws;
    float*    al_s1 = ws;                            // N*4
    float*    al_d1 = al_s1 + (size_t)N * 4;         // N*4
    float*    al_s2 = al_d1 + (size_t)N * 4;         // N
    float*    al_d2 = al_s2 + N;                     // N
    float*    out2  = al_d2 + N;                     // N*64
    float2*   XA    = (float2*)(out2 + (size_t)N * 64); // N*4 float2
    float*    V     = (float*)(XA + (size_t)N * 4);  // 576 (pad 640)
    int*      deg   = (int*)(V + 640);               // N
    int*      offs  = deg + N;                       // N
    int*      bucket_cur  = offs + N;                // 256
    __half*   h2h   = (__half*)(bucket_cur + 256);   // N*64 halves
    __half*   g_h   = h2h + (size_t)N * 64;          // N*64 halves
    int*      pad   = (int*)(g_h + (size_t)N * 64);
    unsigned* ebits   = (unsigned*)((((uintptr_t)pad) + 15) & ~(uintptr_t)15); // capE
    int*      bmeta   = (int*)(ebits + capE);        // capE
    unsigned* csr_se  = (unsigned*)(bmeta + capE);   // capE
    int*      csr_eid = (int*)(csr_se + capE);       // capE

    const int nb = (N + 255) / 256;

    prep1_kernel<<<nb, 256, 0, stream>>>(x, W1, as1, ad1, W2, b1,
                                         al_s1, al_d1, bucket_cur, V, N);
    binA_kernel<<<256, 256, 0, stream>>>(ei, ea, bucket_cur, ebits, bmeta, E, nbuck);
    binB_kernel<<<nbuck, 256, 0, stream>>>(ebits, bmeta, bucket_cur,
                                           deg, offs, csr_se, csr_eid, N);
    aggX_kernel<<<(4 * N + 255) / 256, 256, 0, stream>>>(csr_se, offs, deg,
                                                         al_s1, al_d1, x, We1, ae1, XA, N);
    hx_kernel<<<(N + 15) / 16, 256, 0, stream>>>(XA, V, as2, ad2, h2h, al_s2, al_d2, N);
    msg2_kernel<<<(N + 3) / 4, 256, 0, stream>>>(csr_se, offs, deg, al_s2, al_d2,
                                                 We2, ae2, h2h, out2, N);
    g_kernel<<<(N + 15) / 16, 256, 0, stream>>>(out2, b2, Wr1, g_h, N);
    edge_csr_kernel<<<(N + 3) / 4, 256, 0, stream>>>(csr_se, csr_eid, offs, deg, g_h,
                                                     br1, Wr2, br2, out, N);
}

// Round 2
// 346.521 us; speedup vs baseline: 1.0467x; 1.0404x over previous
//
#include <hip/hip_runtime.h>
#include <hip/hip_bf16.h>
#include <hip/hip_fp16.h>

#define NEG_SLOPE 0.2f
#define NBUCK_MAX 256   // buckets of 512 nodes; 100k nodes -> 196 buckets
#define BCAP 12288      // fixed bucket capacity (mean 8163, sigma ~90 -> 45 sigma slack)

__device__ __forceinline__ float lrelu(float v) { return v >= 0.f ? v : NEG_SLOPE * v; }

__device__ __forceinline__ float wave_sum(float v) {
    for (int o = 32; o; o >>= 1) v += __shfl_down(v, o, 64);
    return v;
}

__device__ __forceinline__ void h8_to_f(const uint4 v, float* f) {
    float2 a = __half22float2(*(const __half2*)&v.x);
    float2 b = __half22float2(*(const __half2*)&v.y);
    float2 c = __half22float2(*(const __half2*)&v.z);
    float2 d = __half22float2(*(const __half2*)&v.w);
    f[0] = a.x; f[1] = a.y; f[2] = b.x; f[3] = b.y;
    f[4] = c.x; f[5] = c.y; f[6] = d.x; f[7] = d.y;
}

// ce1[h] = dot(We1[h*64..], ae1[h*64..]) — wave h computes head h. 256 threads.
__device__ __forceinline__ void compute_ce1(const float* __restrict__ We1,
                                            const float* __restrict__ ae1,
                                            float* ce /*shared[4]*/) {
    int t = threadIdx.x;
    float p = wave_sum(We1[t] * ae1[t]);
    if ((t & 63) == 0) ce[t >> 6] = p;
    __syncthreads();
}

__device__ __forceinline__ float compute_ce2(const float* __restrict__ We2,
                                             const float* __restrict__ ae2,
                                             float* sh /*shared[1]*/) {
    int t = threadIdx.x;
    if (t < 64) {
        float p = wave_sum(We2[t] * ae2[t]);
        if (t == 0) sh[0] = p;
    }
    __syncthreads();
    return sh[0];
}

// ---------------- Layer-1 prep: al_s1/al_d1; init bucket_cur; block 0 computes V -----
__global__ __launch_bounds__(256) void prep1_kernel(
    const float* __restrict__ x, const float* __restrict__ W1,
    const float* __restrict__ as1, const float* __restrict__ ad1,
    const float* __restrict__ W2, const float* __restrict__ b1,
    float* __restrict__ al_s1, float* __restrict__ al_d1,
    int* __restrict__ bucket_cur, float* __restrict__ V, int N) {
    __shared__ float cs0[4], cs1[4], cd0[4], cd1[4];
    int t = threadIdx.x;
    if (blockIdx.x == 0) bucket_cur[t] = t * BCAP;
    {
        float a = as1[t], d = ad1[t], u0 = W1[t], u1 = W1[256 + t];
        float p0 = wave_sum(u0 * a);
        float p1 = wave_sum(u1 * a);
        float q0 = wave_sum(u0 * d);
        float q1 = wave_sum(u1 * d);
        if ((t & 63) == 0) {
            int h = t >> 6;
            cs0[h] = p0; cs1[h] = p1; cd0[h] = q0; cd1[h] = q1;
        }
    }
    __syncthreads();
    int n = blockIdx.x * 256 + t;
    if (n < N) {
        float2 xs = ((const float2*)x)[n];
        float4 vs, vd;
        vs.x = xs.x * cs0[0] + xs.y * cs1[0];
        vs.y = xs.x * cs0[1] + xs.y * cs1[1];
        vs.z = xs.x * cs0[2] + xs.y * cs1[2];
        vs.w = xs.x * cs0[3] + xs.y * cs1[3];
        vd.x = xs.x * cd0[0] + xs.y * cd1[0];
        vd.y = xs.x * cd0[1] + xs.y * cd1[1];
        vd.z = xs.x * cd0[2] + xs.y * cd1[2];
        vd.w = xs.x * cd0[3] + xs.y * cd1[3];
        ((float4*)al_s1)[n] = vs;
        ((float4*)al_d1)[n] = vd;
    }
    // block 0 epilogue: V0[h,j] = W1[0,h,:]@W2^h[:,j], V1 likewise, c = b1@W2
    if (blockIdx.x == 0) {
        int h = t >> 6, j = t & 63;
        float v0 = 0.f, v1 = 0.f;
        for (int k = 0; k < 64; ++k) {
            float w2 = W2[(h * 64 + k) * 64 + j];
            v0 += W1[h * 64 + k] * w2;
            v1 += W1[256 + h * 64 + k] * w2;
        }
        V[t] = v0;
        V[256 + t] = v1;
        if (t < 64) {
            float c = 0.f;
            for (int i = 0; i < 256; ++i) c += b1[i] * W2[i * 64 + t];
            V[512 + t] = c;
        }
    }
}

// ---------------- Pass A: bin edges into fixed-capacity 512-node buckets -------------
// ebits = (src<<15) | ea15 ; bmeta = (dst_local<<21) | eid   (src<2^17, E<2^21)
__global__ __launch_bounds__(256) void binA_kernel(
    const int* __restrict__ ei, const float* __restrict__ ea,
    int* __restrict__ bucket_cur, unsigned* __restrict__ ebits,
    int* __restrict__ bmeta, int E, int nbuck) {
    __shared__ int lcount[NBUCK_MAX];
    __shared__ int lbase[NBUCK_MAX];
    __shared__ int lcur[NBUCK_MAX];
    int chunk = (E + gridDim.x - 1) / gridDim.x;
    int e0 = blockIdx.x * chunk;
    int e1 = min(e0 + chunk, E);
    for (int i = threadIdx.x; i < nbuck; i += 256) lcount[i] = 0;
    __syncthreads();
    for (int e = e0 + threadIdx.x; e < e1; e += 256)
        atomicAdd(&lcount[ei[E + e] >> 9], 1);
    __syncthreads();
    for (int i = threadIdx.x; i < nbuck; i += 256) {
        lbase[i] = lcount[i] ? atomicAdd(&bucket_cur[i], lcount[i]) : 0;
        lcur[i] = 0;
    }
    __syncthreads();
    for (int e = e0 + threadIdx.x; e < e1; e += 256) {
        int d = ei[E + e];
        int b = d >> 9;
        int pos = lbase[b] + atomicAdd(&lcur[b], 1);
        unsigned q = (unsigned)(ea[e] * 32767.f + 0.5f);
        q = min(q, 32767u);
        ebits[pos] = (((unsigned)ei[e]) << 15) | q;
        bmeta[pos] = ((d & 511) << 21) | e;
    }
}

// ---------------- Pass B: per bucket — LDS deg-histogram, local scan, exact scatter ----
// deg/offs written sequentially; csr_se lives in the fixed bucket region.
// (csr_eid no longer produced: final edge kernel runs in original edge order.)
__global__ __launch_bounds__(256) void binB_kernel(
    const unsigned* __restrict__ ebits, const int* __restrict__ bmeta,
    const int* __restrict__ bucket_cur,
    int* __restrict__ deg, int* __restrict__ offs,
    unsigned* __restrict__ csr_se, int N) {
    __shared__ int lcnt[512];
    __shared__ int lofs[512];
    __shared__ int lcur[512];
    int b = blockIdx.x;
    int n0 = b << 9;
    int t = threadIdx.x;
    lcnt[t] = 0; lcnt[t + 256] = 0;
    __syncthreads();
    int bstart = b * BCAP;
    int bend = bucket_cur[b];      // post-binA == region fill end
    for (int p = bstart + t; p < bend; p += 256)
        atomicAdd(&lcnt[((unsigned)bmeta[p]) >> 21], 1);
    __syncthreads();
    int a0 = lcnt[2 * t], a1 = lcnt[2 * t + 1];
    __shared__ int psum[256];
    psum[t] = a0 + a1;
    __syncthreads();
    for (int o = 1; o < 256; o <<= 1) {
        int a = (t >= o) ? psum[t - o] : 0;
        __syncthreads();
        psum[t] += a;
        __syncthreads();
    }
    int excl = psum[t] - (a0 + a1);
    lofs[2 * t] = excl;
    lofs[2 * t + 1] = excl + a0;
    lcur[2 * t] = bstart + excl;
    lcur[2 * t + 1] = bstart + excl + a0;
    __syncthreads();
    for (int i = t; i < 512; i += 256) {
        int n = n0 + i;
        if (n < N) {
            deg[n] = lcnt[i];
            offs[n] = bstart + lofs[i] + lcnt[i];   // segment END (fixed address space)
        }
    }
    for (int p = bstart + t; p < bend; p += 256) {
        int meta = bmeta[p];
        int pos = atomicAdd(&lcur[((unsigned)meta) >> 21], 1);
        csr_se[pos] = ebits[p];
    }
}

// ---------------- Layer-1 aggregation, rank-2, no-max softmax (logits bounded) --------
// Unrolled x2: two edges' loads issued before either edge's exp/FMA work (MLP).
__global__ __launch_bounds__(256) void aggX_kernel(
    const unsigned* __restrict__ csr_se, const int* __restrict__ offs,
    const int* __restrict__ deg,
    const float* __restrict__ al_s1, const float* __restrict__ al_d1,
    const float* __restrict__ x,
    const float* __restrict__ We1, const float* __restrict__ ae1,
    float2* __restrict__ XA, int N) {
    __shared__ float ce[4];
    compute_ce1(We1, ae1, ce);
    int t = blockIdx.x * 256 + threadIdx.x;
    int n = t >> 2, h = t & 3;
    if (n >= N) return;
    int dc = deg[n];
    int start = offs[n] - dc;
    float ald = al_d1[4 * n + h];
    float ceh = ce[h] * (1.f / 32767.f);
    const float2* x2 = (const float2*)x;
    float z = 0.f, X0 = 0.f, X1 = 0.f;
    int j = 0;
    for (; j + 2 <= dc; j += 2) {
        unsigned w0 = csr_se[start + j];
        unsigned w1 = csr_se[start + j + 1];
        int s0 = w0 >> 15, s1 = w1 >> 15;
        float als0 = al_s1[4 * s0 + h];
        float als1 = al_s1[4 * s1 + h];
        float2 xs0 = x2[s0];
        float2 xs1 = x2[s1];
        float e0 = __expf(lrelu(als0 + ald + (float)(w0 & 32767u) * ceh));
        float e1 = __expf(lrelu(als1 + ald + (float)(w1 & 32767u) * ceh));
        z += e0 + e1;
        X0 += e0 * xs0.x + e1 * xs1.x;
        X1 += e0 * xs0.y + e1 * xs1.y;
    }
    if (j < dc) {
        unsigned w = csr_se[start + j];
        int s = w >> 15;
        float als = al_s1[4 * s + h];
        float2 xs = x2[s];
        float ex = __expf(lrelu(als + ald + (float)(w & 32767u) * ceh));
        z += ex;
        X0 += ex * xs.x;
        X1 += ex * xs.y;
    }
    float inv = 1.f / (z + 1e-16f);
    XA[(size_t)4 * n + h] = make_float2(X0 * inv, X1 * inv);
}

// ---------------- h2 from X: 8x64 matvec per node + alpha dots; h2 stored fp16 -------
__global__ __launch_bounds__(256) void hx_kernel(
    const float2* __restrict__ XA, const float* __restrict__ V,
    const float* __restrict__ as2, const float* __restrict__ ad2,
    __half* __restrict__ h2h, float* __restrict__ al_s2, float* __restrict__ al_d2,
    int N) {
    __shared__ float sV0[256], sV1[256], sC[64];
    for (int i = threadIdx.x; i < 256; i += 256) { sV0[i] = V[i]; sV1[i] = V[256 + i]; }
    if (threadIdx.x < 64) sC[threadIdx.x] = V[512 + threadIdx.x];
    __syncthreads();
    int wave = threadIdx.x >> 6, lane = threadIdx.x & 63;
    int n0 = (blockIdx.x * 4 + wave) * 4;
    float a_s = as2[lane], a_d = ad2[lane];
    for (int r = 0; r < 4; ++r) {
        int n = n0 + r;
        if (n >= N) break;
        float acc = sC[lane];
#pragma unroll
        for (int h = 0; h < 4; ++h) {
            float2 xv = XA[4 * n + h];
            acc += xv.x * sV0[h * 64 + lane] + xv.y * sV1[h * 64 + lane];
        }
        h2h[(size_t)n * 64 + lane] = __float2half(acc);
        float sv = wave_sum(acc * a_s);
        float dv = wave_sum(acc * a_d);
        if (lane == 0) { al_s2[n] = sv; al_d2[n] = dv; }
    }
}

// ---------------- Layer-2 fused softmax+message: ex and z computed inline ------------
// Eighth-wave (8 lanes x 8 halves) per edge; wave per node; no-max softmax (bounded
// logits, validated R12). Unrolled x2: 16 edges in flight per wave iteration; both
// h2 row gathers issued before the exp work. Invalid lanes hit row 0 (hot line), ex=0.
__global__ __launch_bounds__(256) void msg2_kernel(
    const unsigned* __restrict__ csr_se, const int* __restrict__ offs,
    const int* __restrict__ deg,
    const float* __restrict__ al_s2, const float* __restrict__ al_d2,
    const float* __restrict__ We2, const float* __restrict__ ae2,
    const __half* __restrict__ h2h, float* __restrict__ out2, int N) {
    __shared__ float sh[1];
    float ce2 = compute_ce2(We2, ae2, sh) * (1.f / 32767.f);
    int wave = threadIdx.x >> 6, lane = threadIdx.x & 63;
    int sub = lane >> 3, sl = lane & 7;
    int n = blockIdx.x * 4 + wave;
    if (n >= N) return;
    int dc = deg[n];
    int start = offs[n] - dc;
    float ald = al_d2[n];
    const uint4* h8 = (const uint4*)h2h;   // row = 8 uint4
    float acc[8] = {0.f, 0.f, 0.f, 0.f, 0.f, 0.f, 0.f, 0.f};
    float z = 0.f;
    for (int j0 = 0; j0 < dc; j0 += 16) {
        int jA = j0 + sub;
        int jB = jA + 8;
        bool vA = jA < dc, vB = jB < dc;
        unsigned wA = vA ? csr_se[start + jA] : 0u;
        unsigned wB = vB ? csr_se[start + jB] : 0u;
        int sA = wA >> 15;
        int sB = wB >> 15;
        uint4 hvA = h8[(size_t)sA * 8 + sl];
        uint4 hvB = h8[(size_t)sB * 8 + sl];
        float exA = 0.f, exB = 0.f;
        if (vA) exA = __expf(lrelu(al_s2[sA] + ald + (float)(wA & 32767u) * ce2));
        if (vB) exB = __expf(lrelu(al_s2[sB] + ald + (float)(wB & 32767u) * ce2));
        float hfA[8], hfB[8];
        h8_to_f(hvA, hfA);
        h8_to_f(hvB, hfB);
#pragma unroll
        for (int k = 0; k < 8; ++k) acc[k] += exA * hfA[k] + exB * hfB[k];
        z += exA + exB;
    }
    // reduce across the 8 sub-groups (lanes sub*8+sl); z reduces identically
#pragma unroll
    for (int k = 0; k < 8; ++k) {
        acc[k] += __shfl_down(acc[k], 32, 64);
        acc[k] += __shfl_down(acc[k], 16, 64);
        acc[k] += __shfl_down(acc[k], 8, 64);
    }
    z += __shfl_down(z, 32, 64);
    z += __shfl_down(z, 16, 64);
    z += __shfl_down(z, 8, 64);
    if (sub == 0) {
        float inv = 1.f / (z + 1e-16f);
        float4* o4 = (float4*)out2;
        o4[(size_t)n * 16 + sl * 2] =
            make_float4(acc[0] * inv, acc[1] * inv, acc[2] * inv, acc[3] * inv);
        o4[(size_t)n * 16 + sl * 2 + 1] =
            make_float4(acc[4] * inv, acc[5] * inv, acc[6] * inv, acc[7] * inv);
    }
}

// ---------------- g = Wr1^T (out2 + b2), stored fp16 ----------------
__global__ __launch_bounds__(256) void g_kernel(
    const float* __restrict__ out2, const float* __restrict__ b2,
    const float* __restrict__ Wr1, __half* __restrict__ g_h, int N) {
    __shared__ float W[64 * 64];
    __shared__ float rows[4][4][64];
    for (int i = threadIdx.x; i < 64 * 64; i += 256) W[i] = Wr1[i];
    __syncthreads();
    int wave = threadIdx.x >> 6, lane = threadIdx.x & 63;
    int n0 = (blockIdx.x * 4 + wave) * 4;
    for (int r = 0; r < 4; ++r) {
        int n = n0 + r;
        rows[wave][r][lane] = (n < N) ? (out2[(size_t)n * 64 + lane] + b2[lane]) : 0.f;
    }
    float a0 = 0.f, a1 = 0.f, a2 = 0.f, a3 = 0.f;
#pragma unroll 8
    for (int k = 0; k < 64; ++k) {
        float w = W[k * 64 + lane];
        a0 += rows[wave][0][k] * w;
        a1 += rows[wave][1][k] * w;
        a2 += rows[wave][2][k] * w;
        a3 += rows[wave][3][k] * w;
    }
    float as[4] = {a0, a1, a2, a3};
    for (int r = 0; r < 4; ++r) {
        int n = n0 + r;
        if (n < N) g_h[(size_t)n * 64 + lane] = __float2half(as[r]);
    }
}

// ---------------- Edge regressor, ORIGINAL edge order ---------------------------------
// Per-edge op with no aggregation: out[e] = sum_k relu(g[src]+g[dst]+br1)_k * Wr2_k + br2.
// Edge order makes ei reads + out writes perfectly coalesced (no scattered 4B stores,
// no RMW partial-line writebacks); the two 128B g-row gathers hit the L2/L3-resident
// 12.8MB g table. Eighth-wave (8 lanes) per edge, 16 contiguous edges per wave-iter.
__global__ __launch_bounds__(256) void edge_kernel(
    const int* __restrict__ ei,
    const __half* __restrict__ g_h,
    const float* __restrict__ br1, const float* __restrict__ Wr2,
    const float* __restrict__ br2, float* __restrict__ out, int E) {
    int wave = threadIdx.x >> 6, lane = threadIdx.x & 63;
    int sub = lane >> 3, sl = lane & 7;
    const uint4* g8 = (const uint4*)g_h;
    float br1v[8], w2[8];
    {
        float4 brA = ((const float4*)br1)[sl * 2], brB = ((const float4*)br1)[sl * 2 + 1];
        br1v[0] = brA.x; br1v[1] = brA.y; br1v[2] = brA.z; br1v[3] = brA.w;
        br1v[4] = brB.x; br1v[5] = brB.y; br1v[6] = brB.z; br1v[7] = brB.w;
        float4 wA = ((const float4*)Wr2)[sl * 2], wB = ((const float4*)Wr2)[sl * 2 + 1];
        w2[0] = wA.x; w2[1] = wA.y; w2[2] = wA.z; w2[3] = wA.w;
        w2[4] = wB.x; w2[5] = wB.y; w2[6] = wB.z; w2[7] = wB.w;
    }
    float br2v = br2[0];
    // each wave owns 64 contiguous edges, processed as 4 iters x (2x8) edges
    int wbase = (blockIdx.x * 4 + wave) * 64;
#pragma unroll
    for (int it = 0; it < 4; ++it) {
        int eA = wbase + it * 16 + sub;
        int eB = eA + 8;
        bool vA = eA < E, vB = eB < E;
        int sA = vA ? ei[eA] : 0;
        int dA = vA ? ei[E + eA] : 0;
        int sB = vB ? ei[eB] : 0;
        int dB = vB ? ei[E + eB] : 0;
        uint4 gsa = g8[(size_t)sA * 8 + sl];
        uint4 gda = g8[(size_t)dA * 8 + sl];
        uint4 gsb = g8[(size_t)sB * 8 + sl];
        uint4 gdb = g8[(size_t)dB * 8 + sl];
        float fsa[8], fda[8], fsb[8], fdb[8];
        h8_to_f(gsa, fsa);
        h8_to_f(gda, fda);
        h8_to_f(gsb, fsb);
        h8_to_f(gdb, fdb);
        float vAa = 0.f, vBa = 0.f;
#pragma unroll
        for (int k = 0; k < 8; ++k) {
            vAa += fmaxf(fsa[k] + fda[k] + br1v[k], 0.f) * w2[k];
            vBa += fmaxf(fsb[k] + fdb[k] + br1v[k], 0.f) * w2[k];
        }
        vAa += __shfl_down(vAa, 4, 64);
        vAa += __shfl_down(vAa, 2, 64);
        vAa += __shfl_down(vAa, 1, 64);
        vBa += __shfl_down(vBa, 4, 64);
        vBa += __shfl_down(vBa, 2, 64);
        vBa += __shfl_down(vBa, 1, 64);
        if (sl == 0) {
            if (vA) out[eA] = vAa + br2v;
            if (vB) out[eB] = vBa + br2v;
        }
    }
}

extern "C" void kernel_launch(void* const* d_in, const int* in_sizes, int n_in,
                              void* d_out, int out_size, void* d_ws, size_t ws_size,
                              hipStream_t stream) {
    const float* x    = (const float*)d_in[0];
    const int*   ei   = (const int*)d_in[1];
    const float* ea   = (const float*)d_in[2];
    const float* W1   = (const float*)d_in[3];
    const float* We1  = (const float*)d_in[4];
    const float* as1  = (const float*)d_in[5];
    const float* ad1  = (const float*)d_in[6];
    const float* ae1  = (const float*)d_in[7];
    const float* b1   = (const float*)d_in[8];
    const float* W2   = (const float*)d_in[9];
    const float* We2  = (const float*)d_in[10];
    const float* as2  = (const float*)d_in[11];
    const float* ad2  = (const float*)d_in[12];
    const float* ae2  = (const float*)d_in[13];
    const float* b2   = (const float*)d_in[14];
    const float* Wr1  = (const float*)d_in[15];
    const float* br1  = (const float*)d_in[16];
    const float* Wr2  = (const float*)d_in[17];
    const float* br2  = (const float*)d_in[18];
    float* out = (float*)d_out;

    const int N = in_sizes[0] / 2;
    const int E = in_sizes[2];
    const int nbuck = (N + 511) >> 9;
    const size_t capE = (size_t)nbuck * BCAP;   // fixed-capacity CSR address space

    // workspace layout (~85 MB)
    float* ws = (float*)d_ws;
    float*    al_s1 = ws;                            // N*4
    float*    al_d1 = al_s1 + (size_t)N * 4;         // N*4
    float*    al_s2 = al_d1 + (size_t)N * 4;         // N
    float*    al_d2 = al_s2 + N;                     // N
    float*    out2  = al_d2 + N;                     // N*64
    float2*   XA    = (float2*)(out2 + (size_t)N * 64); // N*4 float2
    float*    V     = (float*)(XA + (size_t)N * 4);  // 576 (pad 640)
    int*      deg   = (int*)(V + 640);               // N
    int*      offs  = deg + N;                       // N
    int*      bucket_cur  = offs + N;                // 256
    __half*   h2h   = (__half*)(bucket_cur + 256);   // N*64 halves
    __half*   g_h   = h2h + (size_t)N * 64;          // N*64 halves
    int*      pad   = (int*)(g_h + (size_t)N * 64);
    unsigned* ebits   = (unsigned*)((((uintptr_t)pad) + 15) & ~(uintptr_t)15); // capE
    int*      bmeta   = (int*)(ebits + capE);        // capE
    unsigned* csr_se  = (unsigned*)(bmeta + capE);   // capE

    const int nb = (N + 255) / 256;

    prep1_kernel<<<nb, 256, 0, stream>>>(x, W1, as1, ad1, W2, b1,
                                         al_s1, al_d1, bucket_cur, V, N);
    binA_kernel<<<256, 256, 0, stream>>>(ei, ea, bucket_cur, ebits, bmeta, E, nbuck);
    binB_kernel<<<nbuck, 256, 0, stream>>>(ebits, bmeta, bucket_cur,
                                           deg, offs, csr_se, N);
    aggX_kernel<<<(4 * N + 255) / 256, 256, 0, stream>>>(csr_se, offs, deg,
                                                         al_s1, al_d1, x, We1, ae1, XA, N);
    hx_kernel<<<(N + 15) / 16, 256, 0, stream>>>(XA, V, as2, ad2, h2h, al_s2, al_d2, N);
    msg2_kernel<<<(N + 3) / 4, 256, 0, stream>>>(csr_se, offs, deg, al_s2, al_d2,
                                                 We2, ae2, h2h, out2, N);
    g_kernel<<<(N + 15) / 16, 256, 0, stream>>>(out2, b2, Wr1, g_h, N);
    edge_kernel<<<(E + 255) / 256, 256, 0, stream>>>(ei, g_h, br1, Wr2, br2, out, E);
}

// Round 3
// 315.390 us; speedup vs baseline: 1.1500x; 1.0987x over previous
//
#include <hip/hip_runtime.h>
#include <hip/hip_bf16.h>
#include <hip/hip_fp16.h>

#define NEG_SLOPE 0.2f
#define NBUCK_MAX 256   // buckets of 512 nodes; 100k nodes -> 196 buckets
#define BCAP 12288      // fixed bucket capacity (mean 8163, sigma ~90 -> 45 sigma slack)

__device__ __forceinline__ float lrelu(float v) { return v >= 0.f ? v : NEG_SLOPE * v; }

__device__ __forceinline__ float wave_sum(float v) {
    for (int o = 32; o; o >>= 1) v += __shfl_down(v, o, 64);
    return v;
}

__device__ __forceinline__ void h8_to_f(const uint4 v, float* f) {
    float2 a = __half22float2(*(const __half2*)&v.x);
    float2 b = __half22float2(*(const __half2*)&v.y);
    float2 c = __half22float2(*(const __half2*)&v.z);
    float2 d = __half22float2(*(const __half2*)&v.w);
    f[0] = a.x; f[1] = a.y; f[2] = b.x; f[3] = b.y;
    f[4] = c.x; f[5] = c.y; f[6] = d.x; f[7] = d.y;
}

// ce1[h] = dot(We1[h*64..], ae1[h*64..]) — wave h computes head h. 256 threads.
__device__ __forceinline__ void compute_ce1(const float* __restrict__ We1,
                                            const float* __restrict__ ae1,
                                            float* ce /*shared[4]*/) {
    int t = threadIdx.x;
    float p = wave_sum(We1[t] * ae1[t]);
    if ((t & 63) == 0) ce[t >> 6] = p;
    __syncthreads();
}

__device__ __forceinline__ float compute_ce2(const float* __restrict__ We2,
                                             const float* __restrict__ ae2,
                                             float* sh /*shared[1]*/) {
    int t = threadIdx.x;
    if (t < 64) {
        float p = wave_sum(We2[t] * ae2[t]);
        if (t == 0) sh[0] = p;
    }
    __syncthreads();
    return sh[0];
}

// ---------------- Layer-1 prep: al_s1/al_d1; block 0 computes Wr1-folded constants ---
// V layout (global): [0..255]=V0W, [256..511]=V1W, [512..575]=cW, [576..639]=cb2,
// [640..643]=V0.as2, [644..647]=V1.as2, [648..651]=V0.ad2, [652..655]=V1.ad2,
// [656]=c.as2, [657]=c.ad2   (all Wr1/b2/c pushed through the linear tail)
__global__ __launch_bounds__(256) void prep1_kernel(
    const float* __restrict__ x, const float* __restrict__ W1,
    const float* __restrict__ as1, const float* __restrict__ ad1,
    const float* __restrict__ W2, const float* __restrict__ b1,
    const float* __restrict__ Wr1, const float* __restrict__ b2,
    const float* __restrict__ as2, const float* __restrict__ ad2,
    float* __restrict__ al_s1, float* __restrict__ al_d1,
    int* __restrict__ bucket_cur, float* __restrict__ V, int N) {
    __shared__ float cs0[4], cs1[4], cd0[4], cd1[4];
    __shared__ float sV0[256], sV1[256], sc[64];
    int t = threadIdx.x;
    if (blockIdx.x == 0) bucket_cur[t] = t * BCAP;
    {
        float a = as1[t], d = ad1[t], u0 = W1[t], u1 = W1[256 + t];
        float p0 = wave_sum(u0 * a);
        float p1 = wave_sum(u1 * a);
        float q0 = wave_sum(u0 * d);
        float q1 = wave_sum(u1 * d);
        if ((t & 63) == 0) {
            int h = t >> 6;
            cs0[h] = p0; cs1[h] = p1; cd0[h] = q0; cd1[h] = q1;
        }
    }
    __syncthreads();
    int n = blockIdx.x * 256 + t;
    if (n < N) {
        float2 xs = ((const float2*)x)[n];
        float4 vs, vd;
        vs.x = xs.x * cs0[0] + xs.y * cs1[0];
        vs.y = xs.x * cs0[1] + xs.y * cs1[1];
        vs.z = xs.x * cs0[2] + xs.y * cs1[2];
        vs.w = xs.x * cs0[3] + xs.y * cs1[3];
        vd.x = xs.x * cd0[0] + xs.y * cd1[0];
        vd.y = xs.x * cd0[1] + xs.y * cd1[1];
        vd.z = xs.x * cd0[2] + xs.y * cd1[2];
        vd.w = xs.x * cd0[3] + xs.y * cd1[3];
        ((float4*)al_s1)[n] = vs;
        ((float4*)al_d1)[n] = vd;
    }
    // block 0 epilogue: fold W1@W2 (=V0,V1), b1@W2 (=c), then push Wr1/as2/ad2 through
    if (blockIdx.x == 0) {
        int h = t >> 6, j = t & 63;
        float v0 = 0.f, v1 = 0.f;
        for (int k = 0; k < 64; ++k) {
            float w2 = W2[(h * 64 + k) * 64 + j];
            v0 += W1[h * 64 + k] * w2;
            v1 += W1[256 + h * 64 + k] * w2;
        }
        sV0[t] = v0;
        sV1[t] = v1;
        if (t < 64) {
            float c = 0.f;
            for (int i = 0; i < 256; ++i) c += b1[i] * W2[i * 64 + t];
            sc[t] = c;
        }
        __syncthreads();
        float v0w = 0.f, v1w = 0.f;
        for (int k = 0; k < 64; ++k) {
            float wr = Wr1[k * 64 + j];
            v0w += sV0[h * 64 + k] * wr;
            v1w += sV1[h * 64 + k] * wr;
        }
        V[t] = v0w;
        V[256 + t] = v1w;
        if (t < 64) {
            float cw = 0.f, cb = 0.f;
            for (int k = 0; k < 64; ++k) {
                float wr = Wr1[k * 64 + t];
                cw += sc[k] * wr;
                cb += b2[k] * wr;
            }
            V[512 + t] = cw;
            V[576 + t] = cb;
        }
        int lane = t & 63;
        float p0 = wave_sum(sV0[t] * as2[lane]);
        float p1 = wave_sum(sV1[t] * as2[lane]);
        float q0 = wave_sum(sV0[t] * ad2[lane]);
        float q1 = wave_sum(sV1[t] * ad2[lane]);
        if (lane == 0) {
            V[640 + h] = p0; V[644 + h] = p1; V[648 + h] = q0; V[652 + h] = q1;
        }
        if (t < 64) {
            float r0 = wave_sum(sc[t] * as2[t]);
            float r1 = wave_sum(sc[t] * ad2[t]);
            if (t == 0) { V[656] = r0; V[657] = r1; }
        }
    }
}

// ---------------- Pass A: bin edges into fixed-capacity 512-node buckets -------------
// ebits = (src<<15) | ea15 ; bmeta = (dst_local<<21) | eid   (src<2^17, E<2^21)
__global__ __launch_bounds__(256) void binA_kernel(
    const int* __restrict__ ei, const float* __restrict__ ea,
    int* __restrict__ bucket_cur, unsigned* __restrict__ ebits,
    int* __restrict__ bmeta, int E, int nbuck) {
    __shared__ int lcount[NBUCK_MAX];
    __shared__ int lbase[NBUCK_MAX];
    __shared__ int lcur[NBUCK_MAX];
    int chunk = (E + gridDim.x - 1) / gridDim.x;
    int e0 = blockIdx.x * chunk;
    int e1 = min(e0 + chunk, E);
    for (int i = threadIdx.x; i < nbuck; i += 256) lcount[i] = 0;
    __syncthreads();
    for (int e = e0 + threadIdx.x; e < e1; e += 256)
        atomicAdd(&lcount[ei[E + e] >> 9], 1);
    __syncthreads();
    for (int i = threadIdx.x; i < nbuck; i += 256) {
        lbase[i] = lcount[i] ? atomicAdd(&bucket_cur[i], lcount[i]) : 0;
        lcur[i] = 0;
    }
    __syncthreads();
    for (int e = e0 + threadIdx.x; e < e1; e += 256) {
        int d = ei[E + e];
        int b = d >> 9;
        int pos = lbase[b] + atomicAdd(&lcur[b], 1);
        unsigned q = (unsigned)(ea[e] * 32767.f + 0.5f);
        q = min(q, 32767u);
        ebits[pos] = (((unsigned)ei[e]) << 15) | q;
        bmeta[pos] = ((d & 511) << 21) | e;
    }
}

// ---------------- Pass B: per bucket — LDS deg-histogram, local scan, exact scatter ----
__global__ __launch_bounds__(256) void binB_kernel(
    const unsigned* __restrict__ ebits, const int* __restrict__ bmeta,
    const int* __restrict__ bucket_cur,
    int* __restrict__ deg, int* __restrict__ offs,
    unsigned* __restrict__ csr_se, int N) {
    __shared__ int lcnt[512];
    __shared__ int lofs[512];
    __shared__ int lcur[512];
    int b = blockIdx.x;
    int n0 = b << 9;
    int t = threadIdx.x;
    lcnt[t] = 0; lcnt[t + 256] = 0;
    __syncthreads();
    int bstart = b * BCAP;
    int bend = bucket_cur[b];      // post-binA == region fill end
    for (int p = bstart + t; p < bend; p += 256)
        atomicAdd(&lcnt[((unsigned)bmeta[p]) >> 21], 1);
    __syncthreads();
    int a0 = lcnt[2 * t], a1 = lcnt[2 * t + 1];
    __shared__ int psum[256];
    psum[t] = a0 + a1;
    __syncthreads();
    for (int o = 1; o < 256; o <<= 1) {
        int a = (t >= o) ? psum[t - o] : 0;
        __syncthreads();
        psum[t] += a;
        __syncthreads();
    }
    int excl = psum[t] - (a0 + a1);
    lofs[2 * t] = excl;
    lofs[2 * t + 1] = excl + a0;
    lcur[2 * t] = bstart + excl;
    lcur[2 * t + 1] = bstart + excl + a0;
    __syncthreads();
    for (int i = t; i < 512; i += 256) {
        int n = n0 + i;
        if (n < N) {
            deg[n] = lcnt[i];
            offs[n] = bstart + lofs[i] + lcnt[i];   // segment END (fixed address space)
        }
    }
    for (int p = bstart + t; p < bend; p += 256) {
        int meta = bmeta[p];
        int pos = atomicAdd(&lcur[((unsigned)meta) >> 21], 1);
        csr_se[pos] = ebits[p];
    }
}

// ---------------- Layer-1 aggregation, rank-2, no-max softmax (logits bounded) --------
__global__ __launch_bounds__(256) void aggX_kernel(
    const unsigned* __restrict__ csr_se, const int* __restrict__ offs,
    const int* __restrict__ deg,
    const float* __restrict__ al_s1, const float* __restrict__ al_d1,
    const float* __restrict__ x,
    const float* __restrict__ We1, const float* __restrict__ ae1,
    float2* __restrict__ XA, int N) {
    __shared__ float ce[4];
    compute_ce1(We1, ae1, ce);
    int t = blockIdx.x * 256 + threadIdx.x;
    int n = t >> 2, h = t & 3;
    if (n >= N) return;
    int dc = deg[n];
    int start = offs[n] - dc;
    float ald = al_d1[4 * n + h];
    float ceh = ce[h] * (1.f / 32767.f);
    const float2* x2 = (const float2*)x;
    float z = 0.f, X0 = 0.f, X1 = 0.f;
    int j = 0;
    for (; j + 2 <= dc; j += 2) {
        unsigned w0 = csr_se[start + j];
        unsigned w1 = csr_se[start + j + 1];
        int s0 = w0 >> 15, s1 = w1 >> 15;
        float als0 = al_s1[4 * s0 + h];
        float als1 = al_s1[4 * s1 + h];
        float2 xs0 = x2[s0];
        float2 xs1 = x2[s1];
        float e0 = __expf(lrelu(als0 + ald + (float)(w0 & 32767u) * ceh));
        float e1 = __expf(lrelu(als1 + ald + (float)(w1 & 32767u) * ceh));
        z += e0 + e1;
        X0 += e0 * xs0.x + e1 * xs1.x;
        X1 += e0 * xs0.y + e1 * xs1.y;
    }
    if (j < dc) {
        unsigned w = csr_se[start + j];
        int s = w >> 15;
        float als = al_s1[4 * s + h];
        float2 xs = x2[s];
        float ex = __expf(lrelu(als + ald + (float)(w & 32767u) * ceh));
        z += ex;
        X0 += ex * xs.x;
        X1 += ex * xs.y;
    }
    float inv = 1.f / (z + 1e-16f);
    XA[(size_t)4 * n + h] = make_float2(X0 * inv, X1 * inv);
}

// ---------------- th2 = Wr1^T h2 per node, directly from XA and folded constants -----
// th2[n][j] = cW[j] + sum_h XA[n][h].x*V0W[h][j] + XA[n][h].y*V1W[h][j]; fp16 store.
// al_s2/al_d2 from 18 precomputed scalars — no wave reductions, h2 never materialized.
__global__ __launch_bounds__(256) void hx_kernel(
    const float2* __restrict__ XA, const float* __restrict__ V,
    __half* __restrict__ th2h, float* __restrict__ al_s2, float* __restrict__ al_d2,
    int N) {
    __shared__ float sV0[256], sV1[256], sCW[64], sS[18];
    for (int i = threadIdx.x; i < 256; i += 256) { sV0[i] = V[i]; sV1[i] = V[256 + i]; }
    if (threadIdx.x < 64) sCW[threadIdx.x] = V[512 + threadIdx.x];
    if (threadIdx.x < 18) sS[threadIdx.x] = V[640 + threadIdx.x];
    __syncthreads();
    int wave = threadIdx.x >> 6, lane = threadIdx.x & 63;
    int n0 = (blockIdx.x * 4 + wave) * 4;
    for (int r = 0; r < 4; ++r) {
        int n = n0 + r;
        if (n >= N) break;
        float th = sCW[lane];
        float als = sS[16], ald = sS[17];
#pragma unroll
        for (int h = 0; h < 4; ++h) {
            float2 xv = XA[4 * n + h];
            th += xv.x * sV0[h * 64 + lane] + xv.y * sV1[h * 64 + lane];
            als += xv.x * sS[h] + xv.y * sS[4 + h];
            ald += xv.x * sS[8 + h] + xv.y * sS[12 + h];
        }
        th2h[(size_t)n * 64 + lane] = __float2half(th);
        if (lane == 0) { al_s2[n] = als; al_d2[n] = ald; }
    }
}

// ---------------- Layer-2 fused softmax+message, emits fp16 g rows directly ----------
// Aggregates th2 (= Wr1^T h2) rows; g[n] = agg/z + cb2 (b2@Wr1). g_kernel eliminated.
__global__ __launch_bounds__(256) void msg2_kernel(
    const unsigned* __restrict__ csr_se, const int* __restrict__ offs,
    const int* __restrict__ deg,
    const float* __restrict__ al_s2, const float* __restrict__ al_d2,
    const float* __restrict__ We2, const float* __restrict__ ae2,
    const float* __restrict__ V,
    const __half* __restrict__ th2h, __half* __restrict__ g_h, int N) {
    __shared__ float sh[1];
    float ce2 = compute_ce2(We2, ae2, sh) * (1.f / 32767.f);
    int wave = threadIdx.x >> 6, lane = threadIdx.x & 63;
    int sub = lane >> 3, sl = lane & 7;
    int n = blockIdx.x * 4 + wave;
    if (n >= N) return;
    int dc = deg[n];
    int start = offs[n] - dc;
    float ald = al_d2[n];
    const uint4* h8 = (const uint4*)th2h;   // row = 8 uint4
    float acc[8] = {0.f, 0.f, 0.f, 0.f, 0.f, 0.f, 0.f, 0.f};
    float z = 0.f;
    for (int j0 = 0; j0 < dc; j0 += 16) {
        int jA = j0 + sub;
        int jB = jA + 8;
        bool vA = jA < dc, vB = jB < dc;
        unsigned wA = vA ? csr_se[start + jA] : 0u;
        unsigned wB = vB ? csr_se[start + jB] : 0u;
        int sA = wA >> 15;
        int sB = wB >> 15;
        uint4 hvA = h8[(size_t)sA * 8 + sl];
        uint4 hvB = h8[(size_t)sB * 8 + sl];
        float exA = 0.f, exB = 0.f;
        if (vA) exA = __expf(lrelu(al_s2[sA] + ald + (float)(wA & 32767u) * ce2));
        if (vB) exB = __expf(lrelu(al_s2[sB] + ald + (float)(wB & 32767u) * ce2));
        float hfA[8], hfB[8];
        h8_to_f(hvA, hfA);
        h8_to_f(hvB, hfB);
#pragma unroll
        for (int k = 0; k < 8; ++k) acc[k] += exA * hfA[k] + exB * hfB[k];
        z += exA + exB;
    }
    // reduce across the 8 sub-groups (lanes sub*8+sl); z reduces identically
#pragma unroll
    for (int k = 0; k < 8; ++k) {
        acc[k] += __shfl_down(acc[k], 32, 64);
        acc[k] += __shfl_down(acc[k], 16, 64);
        acc[k] += __shfl_down(acc[k], 8, 64);
    }
    z += __shfl_down(z, 32, 64);
    z += __shfl_down(z, 16, 64);
    z += __shfl_down(z, 8, 64);
    if (sub == 0) {
        float inv = 1.f / (z + 1e-16f);
        float4 cA = ((const float4*)(V + 576))[sl * 2];
        float4 cB = ((const float4*)(V + 576))[sl * 2 + 1];
        __half2 p0 = __floats2half2_rn(acc[0] * inv + cA.x, acc[1] * inv + cA.y);
        __half2 p1 = __floats2half2_rn(acc[2] * inv + cA.z, acc[3] * inv + cA.w);
        __half2 p2 = __floats2half2_rn(acc[4] * inv + cB.x, acc[5] * inv + cB.y);
        __half2 p3 = __floats2half2_rn(acc[6] * inv + cB.z, acc[7] * inv + cB.w);
        uint4 o;
        o.x = *(unsigned*)&p0; o.y = *(unsigned*)&p1;
        o.z = *(unsigned*)&p2; o.w = *(unsigned*)&p3;
        ((uint4*)g_h)[(size_t)n * 8 + sl] = o;
    }
}

// ---------------- Edge regressor, ORIGINAL edge order ---------------------------------
// out[e] = sum_k relu(g[src]+g[dst]+br1)_k * Wr2_k + br2; coalesced ei reads/out writes;
// g-row gathers hit the L2/L3-resident 12.8MB g table.
__global__ __launch_bounds__(256) void edge_kernel(
    const int* __restrict__ ei,
    const __half* __restrict__ g_h,
    const float* __restrict__ br1, const float* __restrict__ Wr2,
    const float* __restrict__ br2, float* __restrict__ out, int E) {
    int wave = threadIdx.x >> 6, lane = threadIdx.x & 63;
    int sub = lane >> 3, sl = lane & 7;
    const uint4* g8 = (const uint4*)g_h;
    float br1v[8], w2[8];
    {
        float4 brA = ((const float4*)br1)[sl * 2], brB = ((const float4*)br1)[sl * 2 + 1];
        br1v[0] = brA.x; br1v[1] = brA.y; br1v[2] = brA.z; br1v[3] = brA.w;
        br1v[4] = brB.x; br1v[5] = brB.y; br1v[6] = brB.z; br1v[7] = brB.w;
        float4 wA = ((const float4*)Wr2)[sl * 2], wB = ((const float4*)Wr2)[sl * 2 + 1];
        w2[0] = wA.x; w2[1] = wA.y; w2[2] = wA.z; w2[3] = wA.w;
        w2[4] = wB.x; w2[5] = wB.y; w2[6] = wB.z; w2[7] = wB.w;
    }
    float br2v = br2[0];
    // each wave owns 64 contiguous edges, processed as 4 iters x (2x8) edges
    int wbase = (blockIdx.x * 4 + wave) * 64;
#pragma unroll
    for (int it = 0; it < 4; ++it) {
        int eA = wbase + it * 16 + sub;
        int eB = eA + 8;
        bool vA = eA < E, vB = eB < E;
        int sA = vA ? ei[eA] : 0;
        int dA = vA ? ei[E + eA] : 0;
        int sB = vB ? ei[eB] : 0;
        int dB = vB ? ei[E + eB] : 0;
        uint4 gsa = g8[(size_t)sA * 8 + sl];
        uint4 gda = g8[(size_t)dA * 8 + sl];
        uint4 gsb = g8[(size_t)sB * 8 + sl];
        uint4 gdb = g8[(size_t)dB * 8 + sl];
        float fsa[8], fda[8], fsb[8], fdb[8];
        h8_to_f(gsa, fsa);
        h8_to_f(gda, fda);
        h8_to_f(gsb, fsb);
        h8_to_f(gdb, fdb);
        float vAa = 0.f, vBa = 0.f;
#pragma unroll
        for (int k = 0; k < 8; ++k) {
            vAa += fmaxf(fsa[k] + fda[k] + br1v[k], 0.f) * w2[k];
            vBa += fmaxf(fsb[k] + fdb[k] + br1v[k], 0.f) * w2[k];
        }
        vAa += __shfl_down(vAa, 4, 64);
        vAa += __shfl_down(vAa, 2, 64);
        vAa += __shfl_down(vAa, 1, 64);
        vBa += __shfl_down(vBa, 4, 64);
        vBa += __shfl_down(vBa, 2, 64);
        vBa += __shfl_down(vBa, 1, 64);
        if (sl == 0) {
            if (vA) out[eA] = vAa + br2v;
            if (vB) out[eB] = vBa + br2v;
        }
    }
}

extern "C" void kernel_launch(void* const* d_in, const int* in_sizes, int n_in,
                              void* d_out, int out_size, void* d_ws, size_t ws_size,
                              hipStream_t stream) {
    const float* x    = (const float*)d_in[0];
    const int*   ei   = (const int*)d_in[1];
    const float* ea   = (const float*)d_in[2];
    const float* W1   = (const float*)d_in[3];
    const float* We1  = (const float*)d_in[4];
    const float* as1  = (const float*)d_in[5];
    const float* ad1  = (const float*)d_in[6];
    const float* ae1  = (const float*)d_in[7];
    const float* b1   = (const float*)d_in[8];
    const float* W2   = (const float*)d_in[9];
    const float* We2  = (const float*)d_in[10];
    const float* as2  = (const float*)d_in[11];
    const float* ad2  = (const float*)d_in[12];
    const float* ae2  = (const float*)d_in[13];
    const float* b2   = (const float*)d_in[14];
    const float* Wr1  = (const float*)d_in[15];
    const float* br1  = (const float*)d_in[16];
    const float* Wr2  = (const float*)d_in[17];
    const float* br2  = (const float*)d_in[18];
    float* out = (float*)d_out;

    const int N = in_sizes[0] / 2;
    const int E = in_sizes[2];
    const int nbuck = (N + 511) >> 9;
    const size_t capE = (size_t)nbuck * BCAP;   // fixed-capacity CSR address space

    // workspace layout
    float* ws = (float*)d_ws;
    float*    al_s1 = ws;                            // N*4
    float*    al_d1 = al_s1 + (size_t)N * 4;         // N*4
    float*    al_s2 = al_d1 + (size_t)N * 4;         // N
    float*    al_d2 = al_s2 + N;                     // N
    float2*   XA    = (float2*)(al_d2 + N);          // N*4 float2
    float*    V     = (float*)((((uintptr_t)(XA + (size_t)N * 4)) + 15) & ~(uintptr_t)15); // 658 (pad 704)
    int*      deg   = (int*)(V + 704);               // N
    int*      offs  = deg + N;                       // N
    int*      bucket_cur  = offs + N;                // 256
    __half*   th2h  = (__half*)(bucket_cur + 256);   // N*64 halves (Wr1^T h2)
    __half*   g_h   = th2h + (size_t)N * 64;         // N*64 halves
    int*      pad   = (int*)(g_h + (size_t)N * 64);
    unsigned* ebits   = (unsigned*)((((uintptr_t)pad) + 15) & ~(uintptr_t)15); // capE
    int*      bmeta   = (int*)(ebits + capE);        // capE
    unsigned* csr_se  = (unsigned*)(bmeta + capE);   // capE

    const int nb = (N + 255) / 256;

    prep1_kernel<<<nb, 256, 0, stream>>>(x, W1, as1, ad1, W2, b1, Wr1, b2, as2, ad2,
                                         al_s1, al_d1, bucket_cur, V, N);
    binA_kernel<<<256, 256, 0, stream>>>(ei, ea, bucket_cur, ebits, bmeta, E, nbuck);
    binB_kernel<<<nbuck, 256, 0, stream>>>(ebits, bmeta, bucket_cur,
                                           deg, offs, csr_se, N);
    aggX_kernel<<<(4 * N + 255) / 256, 256, 0, stream>>>(csr_se, offs, deg,
                                                         al_s1, al_d1, x, We1, ae1, XA, N);
    hx_kernel<<<(N + 15) / 16, 256, 0, stream>>>(XA, V, th2h, al_s2, al_d2, N);
    msg2_kernel<<<(N + 3) / 4, 256, 0, stream>>>(csr_se, offs, deg, al_s2, al_d2,
                                                 We2, ae2, V, th2h, g_h, N);
    edge_kernel<<<(E + 255) / 256, 256, 0, stream>>>(ei, g_h, br1, Wr2, br2, out, E);
}

// Round 4
// 280.146 us; speedup vs baseline: 1.2947x; 1.1258x over previous
//
#include <hip/hip_runtime.h>
#include <hip/hip_bf16.h>
#include <hip/hip_fp16.h>

#define NEG_SLOPE 0.2f
#define NBUCK_MAX 256   // buckets of 512 nodes; 100k nodes -> 196 buckets
#define BCAP 12288      // fixed bucket capacity (mean 8163, sigma ~90 -> 45 sigma slack)

__device__ __forceinline__ float lrelu(float v) { return v >= 0.f ? v : NEG_SLOPE * v; }

__device__ __forceinline__ float wave_sum(float v) {
    for (int o = 32; o; o >>= 1) v += __shfl_down(v, o, 64);
    return v;
}

__device__ __forceinline__ void h8_to_f(const uint4 v, float* f) {
    float2 a = __half22float2(*(const __half2*)&v.x);
    float2 b = __half22float2(*(const __half2*)&v.y);
    float2 c = __half22float2(*(const __half2*)&v.z);
    float2 d = __half22float2(*(const __half2*)&v.w);
    f[0] = a.x; f[1] = a.y; f[2] = b.x; f[3] = b.y;
    f[4] = c.x; f[5] = c.y; f[6] = d.x; f[7] = d.y;
}

// ce1[h] = dot(We1[h*64..], ae1[h*64..]) — wave h computes head h. 256 threads.
__device__ __forceinline__ void compute_ce1(const float* __restrict__ We1,
                                            const float* __restrict__ ae1,
                                            float* ce /*shared[4]*/) {
    int t = threadIdx.x;
    float p = wave_sum(We1[t] * ae1[t]);
    if ((t & 63) == 0) ce[t >> 6] = p;
    __syncthreads();
}

__device__ __forceinline__ float compute_ce2(const float* __restrict__ We2,
                                             const float* __restrict__ ae2,
                                             float* sh /*shared[1]*/) {
    int t = threadIdx.x;
    if (t < 64) {
        float p = wave_sum(We2[t] * ae2[t]);
        if (t == 0) sh[0] = p;
    }
    __syncthreads();
    return sh[0];
}

// ---------------- Layer-1 prep: al_s1/al_d1; block 0 computes Wr1-folded constants ---
// V layout (global): [0..255]=V0W, [256..511]=V1W, [512..575]=cW, [576..639]=cb2,
// [640..643]=V0.as2, [644..647]=V1.as2, [648..651]=V0.ad2, [652..655]=V1.ad2,
// [656]=c.as2, [657]=c.ad2   (all Wr1/b2/c pushed through the linear tail)
__global__ __launch_bounds__(256) void prep1_kernel(
    const float* __restrict__ x, const float* __restrict__ W1,
    const float* __restrict__ as1, const float* __restrict__ ad1,
    const float* __restrict__ W2, const float* __restrict__ b1,
    const float* __restrict__ Wr1, const float* __restrict__ b2,
    const float* __restrict__ as2, const float* __restrict__ ad2,
    float* __restrict__ al_s1, float* __restrict__ al_d1,
    int* __restrict__ bucket_cur, float* __restrict__ V, int N) {
    __shared__ float cs0[4], cs1[4], cd0[4], cd1[4];
    __shared__ float sV0[256], sV1[256], sc[64];
    int t = threadIdx.x;
    if (blockIdx.x == 0) bucket_cur[t] = t * BCAP;
    {
        float a = as1[t], d = ad1[t], u0 = W1[t], u1 = W1[256 + t];
        float p0 = wave_sum(u0 * a);
        float p1 = wave_sum(u1 * a);
        float q0 = wave_sum(u0 * d);
        float q1 = wave_sum(u1 * d);
        if ((t & 63) == 0) {
            int h = t >> 6;
            cs0[h] = p0; cs1[h] = p1; cd0[h] = q0; cd1[h] = q1;
        }
    }
    __syncthreads();
    int n = blockIdx.x * 256 + t;
    if (n < N) {
        float2 xs = ((const float2*)x)[n];
        float4 vs, vd;
        vs.x = xs.x * cs0[0] + xs.y * cs1[0];
        vs.y = xs.x * cs0[1] + xs.y * cs1[1];
        vs.z = xs.x * cs0[2] + xs.y * cs1[2];
        vs.w = xs.x * cs0[3] + xs.y * cs1[3];
        vd.x = xs.x * cd0[0] + xs.y * cd1[0];
        vd.y = xs.x * cd0[1] + xs.y * cd1[1];
        vd.z = xs.x * cd0[2] + xs.y * cd1[2];
        vd.w = xs.x * cd0[3] + xs.y * cd1[3];
        ((float4*)al_s1)[n] = vs;
        ((float4*)al_d1)[n] = vd;
    }
    // block 0 epilogue: fold W1@W2 (=V0,V1), b1@W2 (=c), then push Wr1/as2/ad2 through
    if (blockIdx.x == 0) {
        int h = t >> 6, j = t & 63;
        float v0 = 0.f, v1 = 0.f;
        for (int k = 0; k < 64; ++k) {
            float w2 = W2[(h * 64 + k) * 64 + j];
            v0 += W1[h * 64 + k] * w2;
            v1 += W1[256 + h * 64 + k] * w2;
        }
        sV0[t] = v0;
        sV1[t] = v1;
        if (t < 64) {
            float c = 0.f;
            for (int i = 0; i < 256; ++i) c += b1[i] * W2[i * 64 + t];
            sc[t] = c;
        }
        __syncthreads();
        float v0w = 0.f, v1w = 0.f;
        for (int k = 0; k < 64; ++k) {
            float wr = Wr1[k * 64 + j];
            v0w += sV0[h * 64 + k] * wr;
            v1w += sV1[h * 64 + k] * wr;
        }
        V[t] = v0w;
        V[256 + t] = v1w;
        if (t < 64) {
            float cw = 0.f, cb = 0.f;
            for (int k = 0; k < 64; ++k) {
                float wr = Wr1[k * 64 + t];
                cw += sc[k] * wr;
                cb += b2[k] * wr;
            }
            V[512 + t] = cw;
            V[576 + t] = cb;
        }
        int lane = t & 63;
        float p0 = wave_sum(sV0[t] * as2[lane]);
        float p1 = wave_sum(sV1[t] * as2[lane]);
        float q0 = wave_sum(sV0[t] * ad2[lane]);
        float q1 = wave_sum(sV1[t] * ad2[lane]);
        if (lane == 0) {
            V[640 + h] = p0; V[644 + h] = p1; V[648 + h] = q0; V[652 + h] = q1;
        }
        if (t < 64) {
            float r0 = wave_sum(sc[t] * as2[t]);
            float r1 = wave_sum(sc[t] * ad2[t]);
            if (t == 0) { V[656] = r0; V[657] = r1; }
        }
    }
}

// ---------------- Pass A: bin edges into fixed-capacity 512-node buckets -------------
// ebits = (src<<15) | ea15 ; bmeta = (dst_local<<21) | eid   (src<2^17, E<2^21)
__global__ __launch_bounds__(256) void binA_kernel(
    const int* __restrict__ ei, const float* __restrict__ ea,
    int* __restrict__ bucket_cur, unsigned* __restrict__ ebits,
    int* __restrict__ bmeta, int E, int nbuck) {
    __shared__ int lcount[NBUCK_MAX];
    __shared__ int lbase[NBUCK_MAX];
    __shared__ int lcur[NBUCK_MAX];
    int chunk = (E + gridDim.x - 1) / gridDim.x;
    int e0 = blockIdx.x * chunk;
    int e1 = min(e0 + chunk, E);
    for (int i = threadIdx.x; i < nbuck; i += 256) lcount[i] = 0;
    __syncthreads();
    for (int e = e0 + threadIdx.x; e < e1; e += 256)
        atomicAdd(&lcount[ei[E + e] >> 9], 1);
    __syncthreads();
    for (int i = threadIdx.x; i < nbuck; i += 256) {
        lbase[i] = lcount[i] ? atomicAdd(&bucket_cur[i], lcount[i]) : 0;
        lcur[i] = 0;
    }
    __syncthreads();
    for (int e = e0 + threadIdx.x; e < e1; e += 256) {
        int d = ei[E + e];
        int b = d >> 9;
        int pos = lbase[b] + atomicAdd(&lcur[b], 1);
        unsigned q = (unsigned)(ea[e] * 32767.f + 0.5f);
        q = min(q, 32767u);
        ebits[pos] = (((unsigned)ei[e]) << 15) | q;
        bmeta[pos] = ((d & 511) << 21) | e;
    }
}

// ---------------- Pass B: per bucket — LDS deg-histogram, local scan, exact scatter ----
__global__ __launch_bounds__(256) void binB_kernel(
    const unsigned* __restrict__ ebits, const int* __restrict__ bmeta,
    const int* __restrict__ bucket_cur,
    int* __restrict__ deg, int* __restrict__ offs,
    unsigned* __restrict__ csr_se, int N) {
    __shared__ int lcnt[512];
    __shared__ int lofs[512];
    __shared__ int lcur[512];
    int b = blockIdx.x;
    int n0 = b << 9;
    int t = threadIdx.x;
    lcnt[t] = 0; lcnt[t + 256] = 0;
    __syncthreads();
    int bstart = b * BCAP;
    int bend = bucket_cur[b];      // post-binA == region fill end
    for (int p = bstart + t; p < bend; p += 256)
        atomicAdd(&lcnt[((unsigned)bmeta[p]) >> 21], 1);
    __syncthreads();
    int a0 = lcnt[2 * t], a1 = lcnt[2 * t + 1];
    __shared__ int psum[256];
    psum[t] = a0 + a1;
    __syncthreads();
    for (int o = 1; o < 256; o <<= 1) {
        int a = (t >= o) ? psum[t - o] : 0;
        __syncthreads();
        psum[t] += a;
        __syncthreads();
    }
    int excl = psum[t] - (a0 + a1);
    lofs[2 * t] = excl;
    lofs[2 * t + 1] = excl + a0;
    lcur[2 * t] = bstart + excl;
    lcur[2 * t + 1] = bstart + excl + a0;
    __syncthreads();
    for (int i = t; i < 512; i += 256) {
        int n = n0 + i;
        if (n < N) {
            deg[n] = lcnt[i];
            offs[n] = bstart + lofs[i] + lcnt[i];   // segment END (fixed address space)
        }
    }
    for (int p = bstart + t; p < bend; p += 256) {
        int meta = bmeta[p];
        int pos = atomicAdd(&lcur[((unsigned)meta) >> 21], 1);
        csr_se[pos] = ebits[p];
    }
}

// ---------------- Layer-1 aggregation + layer-2 logit scalars --------------------------
// Rank-2 softmax-weighted x aggregation per (node,head); then al_s2/al_d2 from the 18
// folded scalars via a 4-lane shuffle reduce (hx's scalar work absorbed here).
__global__ __launch_bounds__(256) void aggX_kernel(
    const unsigned* __restrict__ csr_se, const int* __restrict__ offs,
    const int* __restrict__ deg,
    const float* __restrict__ al_s1, const float* __restrict__ al_d1,
    const float* __restrict__ x,
    const float* __restrict__ We1, const float* __restrict__ ae1,
    const float* __restrict__ V,
    float2* __restrict__ XA, float* __restrict__ al_s2, float* __restrict__ al_d2,
    int N) {
    __shared__ float ce[4];
    __shared__ float sS[18];
    if (threadIdx.x < 18) sS[threadIdx.x] = V[640 + threadIdx.x];
    compute_ce1(We1, ae1, ce);
    int t = blockIdx.x * 256 + threadIdx.x;
    int n = t >> 2, h = t & 3;
    if (n >= N) return;
    int dc = deg[n];
    int start = offs[n] - dc;
    float ald = al_d1[4 * n + h];
    float ceh = ce[h] * (1.f / 32767.f);
    const float2* x2 = (const float2*)x;
    float z = 0.f, X0 = 0.f, X1 = 0.f;
    int j = 0;
    for (; j + 2 <= dc; j += 2) {
        unsigned w0 = csr_se[start + j];
        unsigned w1 = csr_se[start + j + 1];
        int s0 = w0 >> 15, s1 = w1 >> 15;
        float als0 = al_s1[4 * s0 + h];
        float als1 = al_s1[4 * s1 + h];
        float2 xs0 = x2[s0];
        float2 xs1 = x2[s1];
        float e0 = __expf(lrelu(als0 + ald + (float)(w0 & 32767u) * ceh));
        float e1 = __expf(lrelu(als1 + ald + (float)(w1 & 32767u) * ceh));
        z += e0 + e1;
        X0 += e0 * xs0.x + e1 * xs1.x;
        X1 += e0 * xs0.y + e1 * xs1.y;
    }
    if (j < dc) {
        unsigned w = csr_se[start + j];
        int s = w >> 15;
        float als = al_s1[4 * s + h];
        float2 xs = x2[s];
        float ex = __expf(lrelu(als + ald + (float)(w & 32767u) * ceh));
        z += ex;
        X0 += ex * xs.x;
        X1 += ex * xs.y;
    }
    float inv = 1.f / (z + 1e-16f);
    float xa0 = X0 * inv, xa1 = X1 * inv;
    XA[(size_t)4 * n + h] = make_float2(xa0, xa1);
    // al_s2/al_d2: reduce per-head partials over the 4-lane group
    float ps = xa0 * sS[h] + xa1 * sS[4 + h];
    float pd = xa0 * sS[8 + h] + xa1 * sS[12 + h];
    ps += __shfl_xor(ps, 1, 64); ps += __shfl_xor(ps, 2, 64);
    pd += __shfl_xor(pd, 1, 64); pd += __shfl_xor(pd, 2, 64);
    if (h == 0) {
        al_s2[n] = sS[16] + ps;
        al_d2[n] = sS[17] + pd;
    }
}

// ---------------- Layer-2 rank-8 aggregation: Y[n] = (sum ex*XA[src])/z, w0 = z/z -----
// One lane per edge (thread = (node, quarter)), 32B XA gathers from an L2-resident
// 3.2MB table; exp computed once per edge. Replaces the 128B th2-row msg2.
__global__ __launch_bounds__(256) void msg2y_kernel(
    const unsigned* __restrict__ csr_se, const int* __restrict__ offs,
    const int* __restrict__ deg,
    const float* __restrict__ al_s2, const float* __restrict__ al_d2,
    const float* __restrict__ We2, const float* __restrict__ ae2,
    const float2* __restrict__ XA,
    float2* __restrict__ Yn, float* __restrict__ w0n, int N) {
    __shared__ float sh[1];
    float ce2 = compute_ce2(We2, ae2, sh) * (1.f / 32767.f);
    int t = blockIdx.x * 256 + threadIdx.x;
    int n = t >> 2, q = t & 3;
    if (n >= N) return;
    int dc = deg[n];
    int start = offs[n] - dc;
    float ald = al_d2[n];
    const float4* xa4 = (const float4*)XA;   // node s -> xa4[2s], xa4[2s+1]
    float y0 = 0.f, y1 = 0.f, y2 = 0.f, y3 = 0.f;
    float y4 = 0.f, y5 = 0.f, y6 = 0.f, y7 = 0.f;
    float z = 0.f;
    int j = q;
    for (; j + 4 < dc; j += 8) {
        unsigned wA = csr_se[start + j];
        unsigned wB = csr_se[start + j + 4];
        int sA = wA >> 15, sB = wB >> 15;
        float alsA = al_s2[sA];
        float alsB = al_s2[sB];
        float4 a0 = xa4[(size_t)sA * 2];
        float4 a1 = xa4[(size_t)sA * 2 + 1];
        float4 b0 = xa4[(size_t)sB * 2];
        float4 b1 = xa4[(size_t)sB * 2 + 1];
        float exA = __expf(lrelu(alsA + ald + (float)(wA & 32767u) * ce2));
        float exB = __expf(lrelu(alsB + ald + (float)(wB & 32767u) * ce2));
        z += exA + exB;
        y0 += exA * a0.x + exB * b0.x;
        y1 += exA * a0.y + exB * b0.y;
        y2 += exA * a0.z + exB * b0.z;
        y3 += exA * a0.w + exB * b0.w;
        y4 += exA * a1.x + exB * b1.x;
        y5 += exA * a1.y + exB * b1.y;
        y6 += exA * a1.z + exB * b1.z;
        y7 += exA * a1.w + exB * b1.w;
    }
    if (j < dc) {
        unsigned w = csr_se[start + j];
        int s = w >> 15;
        float als = al_s2[s];
        float4 a0 = xa4[(size_t)s * 2];
        float4 a1 = xa4[(size_t)s * 2 + 1];
        float ex = __expf(lrelu(als + ald + (float)(w & 32767u) * ce2));
        z += ex;
        y0 += ex * a0.x; y1 += ex * a0.y; y2 += ex * a0.z; y3 += ex * a0.w;
        y4 += ex * a1.x; y5 += ex * a1.y; y6 += ex * a1.z; y7 += ex * a1.w;
    }
    // reduce 9 accumulators across the 4-lane group (xor butterfly -> all lanes full)
    y0 += __shfl_xor(y0, 1, 64); y0 += __shfl_xor(y0, 2, 64);
    y1 += __shfl_xor(y1, 1, 64); y1 += __shfl_xor(y1, 2, 64);
    y2 += __shfl_xor(y2, 1, 64); y2 += __shfl_xor(y2, 2, 64);
    y3 += __shfl_xor(y3, 1, 64); y3 += __shfl_xor(y3, 2, 64);
    y4 += __shfl_xor(y4, 1, 64); y4 += __shfl_xor(y4, 2, 64);
    y5 += __shfl_xor(y5, 1, 64); y5 += __shfl_xor(y5, 2, 64);
    y6 += __shfl_xor(y6, 1, 64); y6 += __shfl_xor(y6, 2, 64);
    y7 += __shfl_xor(y7, 1, 64); y7 += __shfl_xor(y7, 2, 64);
    z += __shfl_xor(z, 1, 64); z += __shfl_xor(z, 2, 64);
    float inv = 1.f / (z + 1e-16f);
    // lane q writes (y[2q], y[2q+1]) -> fully coalesced 8B/lane; static-select (no scratch)
    float a = (q == 0) ? y0 : ((q == 1) ? y2 : ((q == 2) ? y4 : y6));
    float b = (q == 0) ? y1 : ((q == 1) ? y3 : ((q == 2) ? y5 : y7));
    Yn[(size_t)4 * n + q] = make_float2(a * inv, b * inv);
    if (q == 0) w0n[n] = z * inv;   // ~1, or 0 for empty segments (kills cW term)
}

// ---------------- g rows from Y: g[n] = w0*cW + cb2 + sum_h Yn[n,h].{x,y}*V{0,1}W ----
__global__ __launch_bounds__(256) void gy_kernel(
    const float2* __restrict__ Yn, const float* __restrict__ w0n,
    const float* __restrict__ V, __half* __restrict__ g_h, int N) {
    __shared__ float sV0[256], sV1[256], sCW[64], sCB[64];
    for (int i = threadIdx.x; i < 256; i += 256) { sV0[i] = V[i]; sV1[i] = V[256 + i]; }
    if (threadIdx.x < 64) sCW[threadIdx.x] = V[512 + threadIdx.x];
    else if (threadIdx.x < 128) sCB[threadIdx.x - 64] = V[512 + threadIdx.x];
    __syncthreads();
    int wave = threadIdx.x >> 6, lane = threadIdx.x & 63;
    int n0 = (blockIdx.x * 4 + wave) * 4;
    for (int r = 0; r < 4; ++r) {
        int n = n0 + r;
        if (n >= N) break;
        float g = sCW[lane] * w0n[n] + sCB[lane];
#pragma unroll
        for (int h = 0; h < 4; ++h) {
            float2 yv = Yn[4 * n + h];
            g += yv.x * sV0[h * 64 + lane] + yv.y * sV1[h * 64 + lane];
        }
        g_h[(size_t)n * 64 + lane] = __float2half(g);
    }
}

// ---------------- Edge regressor, ORIGINAL edge order ---------------------------------
// out[e] = sum_k relu(g[src]+g[dst]+br1)_k * Wr2_k + br2; coalesced ei reads/out writes;
// g-row gathers hit the L2/L3-resident 12.8MB g table.
__global__ __launch_bounds__(256) void edge_kernel(
    const int* __restrict__ ei,
    const __half* __restrict__ g_h,
    const float* __restrict__ br1, const float* __restrict__ Wr2,
    const float* __restrict__ br2, float* __restrict__ out, int E) {
    int wave = threadIdx.x >> 6, lane = threadIdx.x & 63;
    int sub = lane >> 3, sl = lane & 7;
    const uint4* g8 = (const uint4*)g_h;
    float br1v[8], w2[8];
    {
        float4 brA = ((const float4*)br1)[sl * 2], brB = ((const float4*)br1)[sl * 2 + 1];
        br1v[0] = brA.x; br1v[1] = brA.y; br1v[2] = brA.z; br1v[3] = brA.w;
        br1v[4] = brB.x; br1v[5] = brB.y; br1v[6] = brB.z; br1v[7] = brB.w;
        float4 wA = ((const float4*)Wr2)[sl * 2], wB = ((const float4*)Wr2)[sl * 2 + 1];
        w2[0] = wA.x; w2[1] = wA.y; w2[2] = wA.z; w2[3] = wA.w;
        w2[4] = wB.x; w2[5] = wB.y; w2[6] = wB.z; w2[7] = wB.w;
    }
    float br2v = br2[0];
    // each wave owns 64 contiguous edges, processed as 4 iters x (2x8) edges
    int wbase = (blockIdx.x * 4 + wave) * 64;
#pragma unroll
    for (int it = 0; it < 4; ++it) {
        int eA = wbase + it * 16 + sub;
        int eB = eA + 8;
        bool vA = eA < E, vB = eB < E;
        int sA = vA ? ei[eA] : 0;
        int dA = vA ? ei[E + eA] : 0;
        int sB = vB ? ei[eB] : 0;
        int dB = vB ? ei[E + eB] : 0;
        uint4 gsa = g8[(size_t)sA * 8 + sl];
        uint4 gda = g8[(size_t)dA * 8 + sl];
        uint4 gsb = g8[(size_t)sB * 8 + sl];
        uint4 gdb = g8[(size_t)dB * 8 + sl];
        float fsa[8], fda[8], fsb[8], fdb[8];
        h8_to_f(gsa, fsa);
        h8_to_f(gda, fda);
        h8_to_f(gsb, fsb);
        h8_to_f(gdb, fdb);
        float vAa = 0.f, vBa = 0.f;
#pragma unroll
        for (int k = 0; k < 8; ++k) {
            vAa += fmaxf(fsa[k] + fda[k] + br1v[k], 0.f) * w2[k];
            vBa += fmaxf(fsb[k] + fdb[k] + br1v[k], 0.f) * w2[k];
        }
        vAa += __shfl_down(vAa, 4, 64);
        vAa += __shfl_down(vAa, 2, 64);
        vAa += __shfl_down(vAa, 1, 64);
        vBa += __shfl_down(vBa, 4, 64);
        vBa += __shfl_down(vBa, 2, 64);
        vBa += __shfl_down(vBa, 1, 64);
        if (sl == 0) {
            if (vA) out[eA] = vAa + br2v;
            if (vB) out[eB] = vBa + br2v;
        }
    }
}

extern "C" void kernel_launch(void* const* d_in, const int* in_sizes, int n_in,
                              void* d_out, int out_size, void* d_ws, size_t ws_size,
                              hipStream_t stream) {
    const float* x    = (const float*)d_in[0];
    const int*   ei   = (const int*)d_in[1];
    const float* ea   = (const float*)d_in[2];
    const float* W1   = (const float*)d_in[3];
    const float* We1  = (const float*)d_in[4];
    const float* as1  = (const float*)d_in[5];
    const float* ad1  = (const float*)d_in[6];
    const float* ae1  = (const float*)d_in[7];
    const float* b1   = (const float*)d_in[8];
    const float* W2   = (const float*)d_in[9];
    const float* We2  = (const float*)d_in[10];
    const float* as2  = (const float*)d_in[11];
    const float* ad2  = (const float*)d_in[12];
    const float* ae2  = (const float*)d_in[13];
    const float* b2   = (const float*)d_in[14];
    const float* Wr1  = (const float*)d_in[15];
    const float* br1  = (const float*)d_in[16];
    const float* Wr2  = (const float*)d_in[17];
    const float* br2  = (const float*)d_in[18];
    float* out = (float*)d_out;

    const int N = in_sizes[0] / 2;
    const int E = in_sizes[2];
    const int nbuck = (N + 511) >> 9;
    const size_t capE = (size_t)nbuck * BCAP;   // fixed-capacity CSR address space

    // workspace layout
    float* ws = (float*)d_ws;
    float*    al_s1 = ws;                            // N*4
    float*    al_d1 = al_s1 + (size_t)N * 4;         // N*4
    float*    al_s2 = al_d1 + (size_t)N * 4;         // N
    float*    al_d2 = al_s2 + N;                     // N
    float2*   XA    = (float2*)((((uintptr_t)(al_d2 + N)) + 31) & ~(uintptr_t)31); // N*4 float2 (32B aligned)
    float2*   Yn    = (float2*)((((uintptr_t)(XA + (size_t)N * 4)) + 31) & ~(uintptr_t)31); // N*4 float2
    float*    w0n   = (float*)(Yn + (size_t)N * 4);  // N
    float*    V     = (float*)((((uintptr_t)(w0n + N)) + 15) & ~(uintptr_t)15); // 658 (pad 704)
    int*      deg   = (int*)(V + 704);               // N
    int*      offs  = deg + N;                       // N
    int*      bucket_cur  = offs + N;                // 256
    __half*   g_h   = (__half*)(bucket_cur + 256);   // N*64 halves
    int*      pad   = (int*)(g_h + (size_t)N * 64);
    unsigned* ebits   = (unsigned*)((((uintptr_t)pad) + 15) & ~(uintptr_t)15); // capE
    int*      bmeta   = (int*)(ebits + capE);        // capE
    unsigned* csr_se  = (unsigned*)(bmeta + capE);   // capE

    const int nb = (N + 255) / 256;

    prep1_kernel<<<nb, 256, 0, stream>>>(x, W1, as1, ad1, W2, b1, Wr1, b2, as2, ad2,
                                         al_s1, al_d1, bucket_cur, V, N);
    binA_kernel<<<256, 256, 0, stream>>>(ei, ea, bucket_cur, ebits, bmeta, E, nbuck);
    binB_kernel<<<nbuck, 256, 0, stream>>>(ebits, bmeta, bucket_cur,
                                           deg, offs, csr_se, N);
    aggX_kernel<<<(4 * N + 255) / 256, 256, 0, stream>>>(csr_se, offs, deg,
                                                         al_s1, al_d1, x, We1, ae1, V,
                                                         XA, al_s2, al_d2, N);
    msg2y_kernel<<<(4 * N + 255) / 256, 256, 0, stream>>>(csr_se, offs, deg,
                                                          al_s2, al_d2, We2, ae2, XA,
                                                          Yn, w0n, N);
    gy_kernel<<<(N + 15) / 16, 256, 0, stream>>>(Yn, w0n, V, g_h, N);
    edge_kernel<<<(E + 255) / 256, 256, 0, stream>>>(ei, g_h, br1, Wr2, br2, out, E);
}